// Round 13
// baseline (215.759 us; speedup 1.0000x reference)
//
#include <hip/hip_runtime.h>

// UniformKernel: per-column (dim) moving average (K=10, replicate pad) over
// bins axis (n_bins=2048) + per-column normalization. x: (NB, DIM) f32.
//
// out(b,d) = window_sum(b,d) / (width * sum_i w[i]*x[i,d]),
// w[i] = # windows covering row i under edge clamping (K cancels).
//
// R13: R12 (single-global-read, register-resident, 105us) with the 7-barrier
// tree reduce replaced by a barrier-light reduction: 3-step __shfl_xor over
// the 8 row-groups within each wave (register-only), one 2-KB LDS stage
// [16 waves][8 cols], ONE __syncthreads, then 16 broadcast LDS reads.
// Removes the full-block barrier wall between the read and write phases
// (memory pipes drained there). Register-neutral by design: VGPR must stay
// <=64 (R7/R10 lesson: 2 blocks/CU flips to 1 above that).

constexpr int NB   = 2048;
constexpr int DIM  = 32768;
constexpr int DIM4 = DIM / 4;

constexpr int W4   = 8;              // float4 columns per block stripe
constexpr int NBLK = DIM4 / W4;      // 1024 blocks
constexpr int NTHR = 1024;
constexpr int RG   = NTHR / W4;      // 128 row-groups
constexpr int RT   = NB / RG;        // 16 rows per thread (in registers)
constexpr int NW   = NTHR / 64;      // 16 waves

typedef float v4f __attribute__((ext_vector_type(4)));

// # windows covering row i (interior=10; head 15,6,7,8,9; tail 9,8,7,21).
__device__ __forceinline__ float wrow(int i) {
    int a = min(i + 4, NB - 1) - max(i - 5, 0) + 1;
    if (i == 0)      a += 10;
    if (i == NB - 1) a += 15;
    return (float)a;
}

__device__ __forceinline__ v4f shfl4(v4f v, int srcLane) {
    v4f r;
    r.x = __shfl(v.x, srcLane, 64);
    r.y = __shfl(v.y, srcLane, 64);
    r.z = __shfl(v.z, srcLane, 64);
    r.w = __shfl(v.w, srcLane, 64);
    return r;
}

__device__ __forceinline__ v4f shflxor4(v4f v, int mask) {
    v4f r;
    r.x = __shfl_xor(v.x, mask, 64);
    r.y = __shfl_xor(v.y, mask, 64);
    r.z = __shfl_xor(v.z, mask, 64);
    r.w = __shfl_xor(v.w, mask, 64);
    return r;
}

__global__ __launch_bounds__(NTHR, 4) void k_regpass(const float* __restrict__ x,
                                                     const float* __restrict__ bins,
                                                     float* __restrict__ out) {
    const int t    = threadIdx.x;
    const int c    = t & (W4 - 1);        // column lane (0..7)
    const int rg   = t >> 3;              // row group (0..127)
    const int lane = t & 63;
    const int wave = t >> 6;              // 0..15
    const int rgw  = (lane >> 3);         // row group within wave (0..7)
    const int r0   = rg * RT;             // first row of this thread
    const v4f* __restrict__ px = reinterpret_cast<const v4f*>(x)
                                 + ((size_t)blockIdx.x * W4 + c);
    v4f* __restrict__ po = reinterpret_cast<v4f*>(out)
                           + ((size_t)blockIdx.x * W4 + c);

    __shared__ v4f wsums[NW][W4];         // 2 KB  (per-wave column partials)
    __shared__ v4f pub_hi[NW][W4][4];     // wave-edge rgw==7: rows 12..15 (8 KB)
    __shared__ v4f pub_lo[NW][W4][5];     // wave-edge rgw==0: rows 0..4  (10 KB)

    // ---- single global read: rows -> registers, colsum on the fly ----
    v4f xv[RT];
    #pragma unroll
    for (int i = 0; i < RT; ++i)
        xv[i] = px[(size_t)(r0 + i) * DIM4];

    v4f acc = {0.f, 0.f, 0.f, 0.f};
    if (rg == 0 || rg == RG - 1) {
        #pragma unroll
        for (int i = 0; i < RT; ++i) acc += wrow(r0 + i) * xv[i];
    } else {
        #pragma unroll
        for (int i = 0; i < RT; ++i) acc += xv[i];
        acc *= 10.f;
    }

    // ---- wave-level reduce over the 8 row-groups in this wave (no barrier):
    // lanes differing in bits 3/4/5 hold the same column c. Fixed order.
    acc += shflxor4(acc, 8);
    acc += shflxor4(acc, 16);
    acc += shflxor4(acc, 32);
    if (lane < W4) wsums[wave][c] = acc;   // lane==c for lanes 0..7

    // wave-boundary halo publish (2 threads per wave per column)
    if (rgw == 7) {
        #pragma unroll
        for (int j = 0; j < 4; ++j) pub_hi[wave][c][j] = xv[12 + j];
    }
    if (rgw == 0) {
        #pragma unroll
        for (int j = 0; j < 5; ++j) pub_lo[wave][c][j] = xv[j];
    }
    __syncthreads();                      // the ONLY barrier

    // ---- cross-wave: every thread sums the 16 wave partials for its column
    // (same addr across same-c threads -> LDS broadcast, conflict-free).
    v4f ws = wsums[0][c];
    #pragma unroll
    for (int w = 1; w < NW; ++w) ws += wsums[w][c];
    const float width = bins[1] - bins[0];
    v4f sc;
    sc.x = 1.f / (width * ws.x);
    sc.y = 1.f / (width * ws.y);
    sc.z = 1.f / (width * ws.z);
    sc.w = 1.f / (width * ws.w);

    // ---- halo gather: rows r0-4..r0-1 (below this thread's strip) ----
    v4f b[4];
    {
        const int wlo = (wave > 0) ? wave - 1 : 0;
        #pragma unroll
        for (int j = 0; j < 4; ++j) {
            v4f s = shfl4(xv[12 + j], (lane - 8) & 63);
            v4f l = pub_hi[wlo][c][j];
            b[j] = (rgw == 0) ? ((rg == 0) ? xv[0] : l) : s;
        }
    }

    // ---- window pass: S = sum x[r-4..r+5], all registers/halo ----
    v4f S = b[0] + b[1] + b[2] + b[3]
          + xv[0] + xv[1] + xv[2] + xv[3] + xv[4] + xv[5];

    const int whi = (wave < NW - 1) ? wave + 1 : NW - 1;
    #pragma unroll
    for (int r = 0; r < RT; ++r) {
        v4f o = S * sc;
        __builtin_nontemporal_store(o, po + (size_t)(r0 + r) * DIM4);
        if (r < RT - 1) {
            v4f nx;
            if (r < 10) {
                nx = xv[r + 6];
            } else {
                // row r0+16+(r-10): neighbor rg+1's xv[r-10]
                v4f s = shfl4(xv[r - 10], (lane + 8) & 63);
                v4f l = pub_lo[whi][c][r - 10];
                nx = (rgw == 7) ? ((rg == RG - 1) ? xv[15] : l) : s;
            }
            v4f dp = (r >= 4) ? xv[r - 4] : b[r];
            S += nx - dp;
        }
    }
}

extern "C" void kernel_launch(void* const* d_in, const int* in_sizes, int n_in,
                              void* d_out, int out_size, void* d_ws, size_t ws_size,
                              hipStream_t stream) {
    const float* x    = (const float*)d_in[0];   // densities (NB, DIM)
    const float* bins = (const float*)d_in[1];   // (NB,)
    float* out = (float*)d_out;
    k_regpass<<<dim3(NBLK), dim3(NTHR), 0, stream>>>(x, bins, out);
}

// Round 14
// 149.033 us; speedup vs baseline: 1.4477x; 1.4477x over previous
//
#include <hip/hip_runtime.h>

// UniformKernel: per-column (dim) moving average (K=10, replicate pad) over
// bins axis (n_bins=2048) + per-column normalization. x: (NB, DIM) f32.
//
// out(b,d) = window_sum(b,d) / (width * sum_i w[i]*x[i,d]),
// w[i] = # windows covering row i under edge clamping (K cancels).
//
// R14: exact revert to R12 (single-global-read, register-resident, 105us,
// clean traffic) with ONE variable changed: plain stores instead of
// nontemporal. Rationale: x is never re-read after the register load phase,
// so L3 write-back pollution is free; plain stores complete at L2/L3 and
// the kernel needn't wait on HBM drain for 262 MB at end-of-dispatch.
// Each 8-lane group writes a full 128-B line (no RFO expected).
// R13 lesson (3rd spill regression): NO structural changes to this kernel;
// it sits at the register-file edge (xv[16]=64 VGPR + halos + S + sc).

constexpr int NB   = 2048;
constexpr int DIM  = 32768;
constexpr int DIM4 = DIM / 4;

constexpr int W4   = 8;              // float4 columns per block stripe
constexpr int NBLK = DIM4 / W4;      // 1024 blocks
constexpr int NTHR = 1024;
constexpr int RG   = NTHR / W4;      // 128 row-groups
constexpr int RT   = NB / RG;        // 16 rows per thread (in registers)
constexpr int NW   = NTHR / 64;      // 16 waves

typedef float v4f __attribute__((ext_vector_type(4)));

// # windows covering row i (interior=10; head 15,6,7,8,9; tail 9,8,7,21).
__device__ __forceinline__ float wrow(int i) {
    int a = min(i + 4, NB - 1) - max(i - 5, 0) + 1;
    if (i == 0)      a += 10;
    if (i == NB - 1) a += 15;
    return (float)a;
}

__device__ __forceinline__ v4f shfl4(v4f v, int srcLane) {
    v4f r;
    r.x = __shfl(v.x, srcLane, 64);
    r.y = __shfl(v.y, srcLane, 64);
    r.z = __shfl(v.z, srcLane, 64);
    r.w = __shfl(v.w, srcLane, 64);
    return r;
}

__global__ __launch_bounds__(NTHR, 4) void k_regpass(const float* __restrict__ x,
                                                     const float* __restrict__ bins,
                                                     float* __restrict__ out) {
    const int t    = threadIdx.x;
    const int c    = t & (W4 - 1);        // column lane (0..7)
    const int rg   = t >> 3;              // row group (0..127)
    const int lane = t & 63;
    const int wave = t >> 6;              // 0..15
    const int rgw  = (lane >> 3);         // row group within wave (0..7)
    const int r0   = rg * RT;             // first row of this thread
    const v4f* __restrict__ px = reinterpret_cast<const v4f*>(x)
                                 + ((size_t)blockIdx.x * W4 + c);
    v4f* __restrict__ po = reinterpret_cast<v4f*>(out)
                           + ((size_t)blockIdx.x * W4 + c);

    __shared__ v4f sums[RG][W4];          // 16 KB
    __shared__ v4f pub_hi[NW][W4][4];     // wave-edge rgw==7: rows 12..15 (8 KB)
    __shared__ v4f pub_lo[NW][W4][5];     // wave-edge rgw==0: rows 0..4  (10 KB)

    // ---- single global read: rows -> registers, colsum on the fly ----
    v4f xv[RT];
    #pragma unroll
    for (int i = 0; i < RT; ++i)
        xv[i] = px[(size_t)(r0 + i) * DIM4];

    {
        v4f acc = {0.f, 0.f, 0.f, 0.f};
        if (rg == 0 || rg == RG - 1) {
            #pragma unroll
            for (int i = 0; i < RT; ++i) acc += wrow(r0 + i) * xv[i];
        } else {
            #pragma unroll
            for (int i = 0; i < RT; ++i) acc += xv[i];
            acc *= 10.f;
        }
        sums[rg][c] = acc;
    }
    // wave-boundary halo publish (only 2 threads per wave per column)
    if (rgw == 7) {
        #pragma unroll
        for (int j = 0; j < 4; ++j) pub_hi[wave][c][j] = xv[12 + j];
    }
    if (rgw == 0) {
        #pragma unroll
        for (int j = 0; j < 5; ++j) pub_lo[wave][c][j] = xv[j];
    }
    __syncthreads();

    // ---- block-local tree reduce -> per-column scale ----
    #pragma unroll
    for (int s = RG / 2; s > 0; s >>= 1) {
        if (rg < s) sums[rg][c] += sums[rg + s][c];
        __syncthreads();
    }
    const float width = bins[1] - bins[0];
    v4f sc;
    {
        const v4f ws = sums[0][c];
        sc.x = 1.f / (width * ws.x);
        sc.y = 1.f / (width * ws.y);
        sc.z = 1.f / (width * ws.z);
        sc.w = 1.f / (width * ws.w);
    }

    // ---- halo gather: rows r0-4..r0-1 (below) ----
    // below j: neighbor rg-1's xv[12+j]; wave-edge via LDS; rg==0 replicates row 0.
    v4f b[4];
    {
        const int wlo = (wave > 0) ? wave - 1 : 0;
        #pragma unroll
        for (int j = 0; j < 4; ++j) {
            v4f s = shfl4(xv[12 + j], (lane - 8) & 63);
            v4f l = pub_hi[wlo][c][j];
            b[j] = (rgw == 0) ? ((rg == 0) ? xv[0] : l) : s;
        }
    }

    // ---- window pass: S = sum x[r-4..r+5], all from registers/halo ----
    v4f S = b[0] + b[1] + b[2] + b[3]
          + xv[0] + xv[1] + xv[2] + xv[3] + xv[4] + xv[5];

    const int whi = (wave < NW - 1) ? wave + 1 : NW - 1;
    #pragma unroll
    for (int r = 0; r < RT; ++r) {
        v4f o = S * sc;
        po[(size_t)(r0 + r) * DIM4] = o;   // plain store (R14 A/B: was nt)
        if (r < RT - 1) {
            v4f nx;
            if (r < 10) {
                nx = xv[r + 6];
            } else {
                // row r0+16+(r-10): neighbor rg+1's xv[r-10]
                v4f s = shfl4(xv[r - 10], (lane + 8) & 63);
                v4f l = pub_lo[whi][c][r - 10];
                nx = (rgw == 7) ? ((rg == RG - 1) ? xv[15] : l) : s;
            }
            v4f dp = (r >= 4) ? xv[r - 4] : b[r];
            S += nx - dp;
        }
    }
}

extern "C" void kernel_launch(void* const* d_in, const int* in_sizes, int n_in,
                              void* d_out, int out_size, void* d_ws, size_t ws_size,
                              hipStream_t stream) {
    const float* x    = (const float*)d_in[0];   // densities (NB, DIM)
    const float* bins = (const float*)d_in[1];   // (NB,)
    float* out = (float*)d_out;
    k_regpass<<<dim3(NBLK), dim3(NTHR), 0, stream>>>(x, bins, out);
}

// Round 15
// 106.772 us; speedup vs baseline: 2.0207x; 1.3958x over previous
//
#include <hip/hip_runtime.h>

// UniformKernel: per-column (dim) moving average (K=10, replicate pad) over
// bins axis (n_bins=2048) + per-column normalization. x: (NB, DIM) f32.
//
// out(b,d) = window_sum(b,d) / (width * sum_i w[i]*x[i,d]),
// w[i] = # windows covering row i under edge clamping (K cancels).
//
// R15 == R12 verbatim (proven best: 105.3us, minimal 530 MB fabric traffic).
// Design ledger:
//  - single global read: each thread holds 16 rows x 1 float4 col in regs
//    (64 VGPR exactly); colsum on the fly; block-local tree reduce -> scale;
//    window pass entirely from registers + neighbor halos (shfl / LDS pub).
//  - NT STORES REQUIRED: R14 A/B (plain stores, byte-identical traffic)
//    regressed 105->149us -- write-allocate thrashes L2/L3 and evicts the
//    x lines that give the read phase its ~50% L3 hit rate.
//  - register ceiling proven: W4=8/128-B segments forced (wider stripe
//    needs >64 VGPR for xv); restructures spill (R7/R10/R13: -90/-74/-110us).
//  - fabric floor 530 MB @ ~6.4 TB/s ~= 83us; this kernel runs ~79% of it
//    (DRAM granularity of 128-B column-striped access is the residual).

constexpr int NB   = 2048;
constexpr int DIM  = 32768;
constexpr int DIM4 = DIM / 4;

constexpr int W4   = 8;              // float4 columns per block stripe
constexpr int NBLK = DIM4 / W4;      // 1024 blocks
constexpr int NTHR = 1024;
constexpr int RG   = NTHR / W4;      // 128 row-groups
constexpr int RT   = NB / RG;        // 16 rows per thread (in registers)
constexpr int NW   = NTHR / 64;      // 16 waves

typedef float v4f __attribute__((ext_vector_type(4)));

// # windows covering row i (interior=10; head 15,6,7,8,9; tail 9,8,7,21).
__device__ __forceinline__ float wrow(int i) {
    int a = min(i + 4, NB - 1) - max(i - 5, 0) + 1;
    if (i == 0)      a += 10;
    if (i == NB - 1) a += 15;
    return (float)a;
}

__device__ __forceinline__ v4f shfl4(v4f v, int srcLane) {
    v4f r;
    r.x = __shfl(v.x, srcLane, 64);
    r.y = __shfl(v.y, srcLane, 64);
    r.z = __shfl(v.z, srcLane, 64);
    r.w = __shfl(v.w, srcLane, 64);
    return r;
}

__global__ __launch_bounds__(NTHR, 4) void k_regpass(const float* __restrict__ x,
                                                     const float* __restrict__ bins,
                                                     float* __restrict__ out) {
    const int t    = threadIdx.x;
    const int c    = t & (W4 - 1);        // column lane (0..7)
    const int rg   = t >> 3;              // row group (0..127)
    const int lane = t & 63;
    const int wave = t >> 6;              // 0..15
    const int rgw  = (lane >> 3);         // row group within wave (0..7)
    const int r0   = rg * RT;             // first row of this thread
    const v4f* __restrict__ px = reinterpret_cast<const v4f*>(x)
                                 + ((size_t)blockIdx.x * W4 + c);
    v4f* __restrict__ po = reinterpret_cast<v4f*>(out)
                           + ((size_t)blockIdx.x * W4 + c);

    __shared__ v4f sums[RG][W4];          // 16 KB
    __shared__ v4f pub_hi[NW][W4][4];     // wave-edge rgw==7: rows 12..15 (8 KB)
    __shared__ v4f pub_lo[NW][W4][5];     // wave-edge rgw==0: rows 0..4  (10 KB)

    // ---- single global read: rows -> registers, colsum on the fly ----
    v4f xv[RT];
    #pragma unroll
    for (int i = 0; i < RT; ++i)
        xv[i] = px[(size_t)(r0 + i) * DIM4];

    {
        v4f acc = {0.f, 0.f, 0.f, 0.f};
        if (rg == 0 || rg == RG - 1) {
            #pragma unroll
            for (int i = 0; i < RT; ++i) acc += wrow(r0 + i) * xv[i];
        } else {
            #pragma unroll
            for (int i = 0; i < RT; ++i) acc += xv[i];
            acc *= 10.f;
        }
        sums[rg][c] = acc;
    }
    // wave-boundary halo publish (only 2 threads per wave per column)
    if (rgw == 7) {
        #pragma unroll
        for (int j = 0; j < 4; ++j) pub_hi[wave][c][j] = xv[12 + j];
    }
    if (rgw == 0) {
        #pragma unroll
        for (int j = 0; j < 5; ++j) pub_lo[wave][c][j] = xv[j];
    }
    __syncthreads();

    // ---- block-local tree reduce -> per-column scale ----
    #pragma unroll
    for (int s = RG / 2; s > 0; s >>= 1) {
        if (rg < s) sums[rg][c] += sums[rg + s][c];
        __syncthreads();
    }
    const float width = bins[1] - bins[0];
    v4f sc;
    {
        const v4f ws = sums[0][c];
        sc.x = 1.f / (width * ws.x);
        sc.y = 1.f / (width * ws.y);
        sc.z = 1.f / (width * ws.z);
        sc.w = 1.f / (width * ws.w);
    }

    // ---- halo gather: rows r0-4..r0-1 (below) ----
    // below j: neighbor rg-1's xv[12+j]; wave-edge via LDS; rg==0 replicates row 0.
    v4f b[4];
    {
        const int wlo = (wave > 0) ? wave - 1 : 0;
        #pragma unroll
        for (int j = 0; j < 4; ++j) {
            v4f s = shfl4(xv[12 + j], (lane - 8) & 63);
            v4f l = pub_hi[wlo][c][j];
            b[j] = (rgw == 0) ? ((rg == 0) ? xv[0] : l) : s;
        }
    }

    // ---- window pass: S = sum x[r-4..r+5], all from registers/halo ----
    v4f S = b[0] + b[1] + b[2] + b[3]
          + xv[0] + xv[1] + xv[2] + xv[3] + xv[4] + xv[5];

    const int whi = (wave < NW - 1) ? wave + 1 : NW - 1;
    #pragma unroll
    for (int r = 0; r < RT; ++r) {
        v4f o = S * sc;
        __builtin_nontemporal_store(o, po + (size_t)(r0 + r) * DIM4);
        if (r < RT - 1) {
            v4f nx;
            if (r < 10) {
                nx = xv[r + 6];
            } else {
                // row r0+16+(r-10): neighbor rg+1's xv[r-10]
                v4f s = shfl4(xv[r - 10], (lane + 8) & 63);
                v4f l = pub_lo[whi][c][r - 10];
                nx = (rgw == 7) ? ((rg == RG - 1) ? xv[15] : l) : s;
            }
            v4f dp = (r >= 4) ? xv[r - 4] : b[r];
            S += nx - dp;
        }
    }
}

extern "C" void kernel_launch(void* const* d_in, const int* in_sizes, int n_in,
                              void* d_out, int out_size, void* d_ws, size_t ws_size,
                              hipStream_t stream) {
    const float* x    = (const float*)d_in[0];   // densities (NB, DIM)
    const float* bins = (const float*)d_in[1];   // (NB,)
    float* out = (float*)d_out;
    k_regpass<<<dim3(NBLK), dim3(NTHR), 0, stream>>>(x, bins, out);
}